// Round 3
// baseline (141.202 us; speedup 1.0000x reference)
//
#include <hip/hip_runtime.h>
#include <hip/hip_bf16.h>

// Problem constants (EdgeAwareMultiHeadAttention)
constexpr int Bb   = 4;
constexpr int Nn   = 256;
constexpr int HID  = 256;
constexpr int Ee   = 64;
constexpr int Hh   = 4;
constexpr int OUTc = 128;   // HID/2
constexpr int Dd   = 32;    // OUT/H
constexpr int AGG  = 260;   // H*(2D+1)

typedef __attribute__((ext_vector_type(8))) short short8;
typedef __attribute__((ext_vector_type(4))) float floatx4;
typedef __attribute__((ext_vector_type(2))) float floatx2;

// HW packed f32x2 -> bf16x2 (v_cvt_pk_bf16_f32, RNE)
__device__ __forceinline__ unsigned pk2(float a, float b) {
    union { __hip_bfloat162 h; unsigned u; } cv;
    cv.h = __float22bfloat162_rn(float2{a, b});
    return cv.u;
}

__device__ __forceinline__ short8 pack8(floatx4 f0, floatx4 f1) {
    union { short8 s; unsigned u[4]; } r;
    r.u[0] = pk2(f0[0], f0[1]);
    r.u[1] = pk2(f0[2], f0[3]);
    r.u[2] = pk2(f1[0], f1[1]);
    r.u[3] = pk2(f1[2], f1[3]);
    return r.s;
}

// async global->LDS, 16B per lane. dst must be wave-uniform (HW adds lane*16).
__device__ __forceinline__ void gload16(const float* g, float* l) {
    __builtin_amdgcn_global_load_lds(
        (const __attribute__((address_space(1))) void*)g,
        (__attribute__((address_space(3))) void*)l, 16, 0, 0);
}

// ---------------- Single fused kernel: one block per bn ----------------
// Folds all former prep work in-block (W_V frag pack via 4KB LDS window, fp32
// q-GEMV + u-projection, direct W_R reads) so there is ONE launch, zero
// workspace traffic, zero inter-kernel gaps. LDS kept at 38.9KB -> 4 blocks/CU
// (grid 1024 = one balanced round). Main loop identical to R2 (async
// global_load_lds double-buffer, counted vmcnt(4)).
__global__ __launch_bounds__(256, 2)
void eama_fused(const float* __restrict__ h_x, const float* __restrict__ h_e,
                const float* __restrict__ h_m,
                const float* __restrict__ W_Q, const float* __restrict__ W_K,
                const float* __restrict__ W_V, const float* __restrict__ W_R,
                float* __restrict__ out)
{
    // 32KB staging: [wave][buf][chunk j][lane][4 floats]. Dead after the main
    // loop; its 8192 floats are reused for the whole epilogue (per-wave regions).
    __shared__ __align__(16) float sStage[4][2][4][64][4];
    __shared__ __align__(16) float sS[4][16][4];          // score patch (prologue: sU alias)
    __shared__ __align__(16) unsigned short sWin[256 * 8];// 4KB W_V frag window
    __shared__ __align__(16) float sQp[256];              // q split-k partials / q

    const int tid  = threadIdx.x;
    const int lane = tid & 63;
    const int w    = tid >> 6;
    const int ncol = lane & 15;
    const int q8   = lane >> 4;
    const int bn   = blockIdx.x;
    const float maskv = h_m[bn];

    const float* heb = h_e + (size_t)bn * Nn * Ee;
    // per-lane global row base (row = w*64 + it*16 + ncol), q8 selects the 32B column slot
    const float* arq = heb + (size_t)(w * 64 + ncol) * Ee + q8 * 8;

    // tile it -> buf: 4 async 1KB copies; LDS dst is wave-uniform, HW adds lane*16
    #define STAGE(it_, buf_) do { \
        const float* ar_ = arq + (size_t)(it_) * 16 * Ee; \
        gload16(ar_,      &sStage[w][buf_][0][0][0]); \
        gload16(ar_ + 4,  &sStage[w][buf_][1][0][0]); \
        gload16(ar_ + 32, &sStage[w][buf_][2][0][0]); \
        gload16(ar_ + 36, &sStage[w][buf_][3][0][0]); \
    } while (0)

    // Kick off h_e HBM fetch for tiles 0/1 immediately; the prologue below
    // (L2-resident weight work) hides the latency.
    STAGE(0, 0);
    STAGE(1, 1);

    // ---- W_V fragment pack through the 4KB window (4 chunks of 256 frags) ----
    // frag e: row = (e>>7)*16 + (e&15) of W_V, k0 = ((e>>6)&1)*32 + ((e>>4)&3)*8.
    // chunk c holds e in [c*256, c*256+256); thread packs e = c*256+tid.
    short8 bfV[8][2];
    {
        const int ncol_e = tid & 15;
        const int q8_e   = (tid >> 4) & 3;
        const int ks_e   = (tid >> 6) & 1;
        const int cthi   = tid >> 7;
        #pragma unroll
        for (int c = 0; c < 4; ++c) {
            const int ct = c * 2 + cthi;
            const float* row = W_V + (size_t)(ct * 16 + ncol_e) * Ee + ks_e * 32 + q8_e * 8;
            short8 v = pack8(*(const floatx4*)row, *(const floatx4*)(row + 4));
            *(short8*)&sWin[tid * 8] = v;
            __syncthreads();
            // lane l needs frags (4c+m)*64 + l  ->  bfV[2c + (m>>1)][m&1]
            #pragma unroll
            for (int m = 0; m < 4; ++m)
                bfV[c * 2 + (m >> 1)][m & 1] = *(const short8*)&sWin[(m * 64 + lane) * 8];
            __syncthreads();
        }
    }

    // ---- q[c] = W_Q[c,:] . h_x[bn,:]  (fp32, split-k over 2 halves) ----
    {
        const int c = tid & 127, half = tid >> 7;
        const float* wq = W_Q + (size_t)c * HID + half * 128;
        const float* xr = h_x + (size_t)bn * HID + half * 128;
        float acc = 0.f;
        #pragma unroll
        for (int i = 0; i < 32; ++i) {
            floatx4 a = *(const floatx4*)(wq + i * 4);
            floatx4 x = *(const floatx4*)(xr + i * 4);
            acc = fmaf(a[0], x[0], fmaf(a[1], x[1], fmaf(a[2], x[2], fmaf(a[3], x[3], acc))));
        }
        sQp[tid] = acc;
    }
    __syncthreads();
    if (tid < 128) sQp[tid] += sQp[tid + 128];
    __syncthreads();

    // ---- u[h][e] = (q[h*32..] . W_K[...,e]) * rsqrt(D), into sU (aliases sS) ----
    float* sU = &sS[0][0][0];
    {
        const int h = tid >> 6, e = tid & 63;
        float acc = 0.f;
        #pragma unroll
        for (int d = 0; d < 32; ++d)
            acc = fmaf(sQp[h * 32 + d], W_K[(size_t)(h * Dd + d) * Ee + e], acc);
        sU[h * 64 + e] = acc * 0.1767766952966369f;
    }
    __syncthreads();

    // pack bu0/bu1 B-fragments: row ncol (= head) valid for ncol<4, else zero
    short8 bu0 = {0, 0, 0, 0, 0, 0, 0, 0};
    short8 bu1 = {0, 0, 0, 0, 0, 0, 0, 0};
    if (ncol < Hh) {
        bu0 = pack8(*(const floatx4*)&sU[ncol * 64 + q8 * 8],
                    *(const floatx4*)&sU[ncol * 64 + q8 * 8 + 4]);
        bu1 = pack8(*(const floatx4*)&sU[ncol * 64 + 32 + q8 * 8],
                    *(const floatx4*)&sU[ncol * 64 + 32 + q8 * 8 + 4]);
    }
    __syncthreads();   // cross-wave sU reads done before main loop reuses sS

    float vs[8], vm[8], asumH = 0.f;
    #pragma unroll
    for (int ct = 0; ct < 8; ++ct) { vs[ct] = 0.f; vm[ct] = -3.402823466e38f; }

    #pragma unroll
    for (int it = 0; it < 4; ++it) {
        const int buf = it & 1;
        // counted wait: 4 younger staging loads (next tile) may stay in flight
        if (it < 3) asm volatile("s_waitcnt vmcnt(4)" ::: "memory");
        else        asm volatile("s_waitcnt vmcnt(0)" ::: "memory");

        floatx4 c0 = *(const floatx4*)&sStage[w][buf][0][lane][0];
        floatx4 c1 = *(const floatx4*)&sStage[w][buf][1][lane][0];
        floatx4 c2 = *(const floatx4*)&sStage[w][buf][2][lane][0];
        floatx4 c3 = *(const floatx4*)&sStage[w][buf][3][lane][0];
        short8 af0 = pack8(c0, c1);
        short8 af1 = pack8(c2, c3);
        if (it < 2) {
            // ds_reads of this buf must retire before the async overwrite can land
            asm volatile("s_waitcnt lgkmcnt(0)" ::: "memory");
            STAGE(it + 2, buf);
        }

        floatx4 accV[8], accS = (floatx4){0, 0, 0, 0};
        #pragma unroll
        for (int ct = 0; ct < 8; ++ct) accV[ct] = (floatx4){0, 0, 0, 0};
        #pragma unroll
        for (int ct = 0; ct < 8; ++ct) {
            accV[ct] = __builtin_amdgcn_mfma_f32_16x16x32_bf16(af0, bfV[ct][0], accV[ct], 0, 0, 0);
            accV[ct] = __builtin_amdgcn_mfma_f32_16x16x32_bf16(af1, bfV[ct][1], accV[ct], 0, 0, 0);
        }
        accS = __builtin_amdgcn_mfma_f32_16x16x32_bf16(af0, bu0, accS, 0, 0, 0);
        accS = __builtin_amdgcn_mfma_f32_16x16x32_bf16(af1, bu1, accS, 0, 0, 0);

        // scores -> per-wave LDS patch (same-wave write/read; program order holds)
        if (ncol < Hh) {
            #pragma unroll
            for (int r = 0; r < 4; ++r)
                sS[w][q8 * 4 + r][ncol] = (maskv != 0.f) ? accS[r] : -1e30f;
        }
        __builtin_amdgcn_wave_barrier();

        #pragma unroll
        for (int r = 0; r < 4; ++r) {
            floatx4 sc = *(const floatx4*)&sS[w][q8 * 4 + r][0];
            float e0 = __expf(sc[0]), e1 = __expf(sc[1]);
            float e2 = __expf(sc[2]), e3 = __expf(sc[3]);
            float inv = 1.f / ((e0 + e1) + (e2 + e3));
            float a0 = e0 * inv, a1 = e1 * inv, a2 = e2 * inv, a3 = e3 * inv;
            asumH += (ncol & 2) ? ((ncol & 1) ? a3 : a2) : ((ncol & 1) ? a1 : a0);
            float p;
            p = a0 * accV[0][r]; vs[0] += p; vm[0] = fmaxf(vm[0], p);
            p = a0 * accV[1][r]; vs[1] += p; vm[1] = fmaxf(vm[1], p);
            p = a1 * accV[2][r]; vs[2] += p; vm[2] = fmaxf(vm[2], p);
            p = a1 * accV[3][r]; vs[3] += p; vm[3] = fmaxf(vm[3], p);
            p = a2 * accV[4][r]; vs[4] += p; vm[4] = fmaxf(vm[4], p);
            p = a2 * accV[5][r]; vs[5] += p; vm[5] = fmaxf(vm[5], p);
            p = a3 * accV[6][r]; vs[6] += p; vm[6] = fmaxf(vm[6], p);
            p = a3 * accV[7][r]; vs[7] += p; vm[7] = fmaxf(vm[7], p);
        }
        __builtin_amdgcn_wave_barrier();   // sS reused next tile
    }
    #undef STAGE

    // q8-group reduction (once per wave)
    #pragma unroll
    for (int ct = 0; ct < 8; ++ct) {
        vs[ct] += __shfl_xor(vs[ct], 16, 64);
        vs[ct] += __shfl_xor(vs[ct], 32, 64);
        vm[ct] = fmaxf(vm[ct], __shfl_xor(vm[ct], 16, 64));
        vm[ct] = fmaxf(vm[ct], __shfl_xor(vm[ct], 32, 64));
    }
    asumH += __shfl_xor(asumH, 16, 64);
    asumH += __shfl_xor(asumH, 32, 64);

    // ---- epilogue in the dead sStage area (per-wave region = its own 2048 floats) ----
    float* SB = &sStage[0][0][0][0][0];
    // wave w: sVS at [w*2048, +128), sVM at [w*2048+128, +128), sAS at [w*2048+256, +4)
    if (lane < 16) {
        #pragma unroll
        for (int ct = 0; ct < 8; ++ct) {
            SB[w * 2048 + ct * 16 + lane]       = vs[ct];
            SB[w * 2048 + 128 + ct * 16 + lane] = vm[ct];
        }
    }
    if (lane < Hh) SB[w * 2048 + 256 + lane] = asumH;
    __syncthreads();
    if (tid < Hh) {
        SB[512 + tid] = 1e-8f +
            (SB[0 * 2048 + 256 + tid] + SB[1 * 2048 + 256 + tid]) +
            (SB[2 * 2048 + 256 + tid] + SB[3 * 2048 + 256 + tid]);
    }
    __syncthreads();
    if (tid < OUTc) {
        float vsum = (SB[0 * 2048 + tid] + SB[1 * 2048 + tid]) +
                     (SB[2 * 2048 + tid] + SB[3 * 2048 + tid]);
        float vmax = fmaxf(fmaxf(SB[0 * 2048 + 128 + tid], SB[1 * 2048 + 128 + tid]),
                           fmaxf(SB[2 * 2048 + 128 + tid], SB[3 * 2048 + 128 + tid]));
        const int h = tid >> 5, d = tid & 31;
        SB[768 + h * 65 + d]      = vsum / SB[512 + h];
        SB[768 + h * 65 + 33 + d] = vmax;
        if (tid < Hh) SB[768 + tid * 65 + 32] = SB[512 + tid];
    }
    __syncthreads();
    // fused W_R GEMV reading W_R directly (row-contiguous per thread, L2-resident):
    // out[c] = sum_j M[j] * W_R[c*260 + j]; 2 j-halves of 130 across 256 threads
    {
        const int c = tid & 127, part = tid >> 7;
        const int j0 = part * 130;
        const float* wr = W_R + (size_t)c * AGG + j0;   // 8B-aligned (260, 130 even)
        const float* sM = SB + 768;
        float a0 = 0.f, a1 = 0.f, a2 = 0.f, a3 = 0.f;
        #pragma unroll 8
        for (int j = 0; j < 128; j += 4) {
            floatx2 A  = *(const floatx2*)(wr + j);
            floatx2 Bv = *(const floatx2*)(wr + j + 2);
            a0 = fmaf(sM[j0 + j],     A[0],  a0);
            a1 = fmaf(sM[j0 + j + 1], A[1],  a1);
            a2 = fmaf(sM[j0 + j + 2], Bv[0], a2);
            a3 = fmaf(sM[j0 + j + 3], Bv[1], a3);
        }
        floatx2 T = *(const floatx2*)(wr + 128);
        a0 = fmaf(sM[j0 + 128], T[0], a0);
        a1 = fmaf(sM[j0 + 129], T[1], a1);
        SB[1100 + part * 128 + c] = (a0 + a1) + (a2 + a3);
    }
    __syncthreads();
    if (tid < OUTc)
        out[(size_t)bn * OUTc + tid] = SB[1100 + tid] + SB[1100 + 128 + tid];
}

extern "C" void kernel_launch(void* const* d_in, const int* in_sizes, int n_in,
                              void* d_out, int out_size, void* d_ws, size_t ws_size,
                              hipStream_t stream) {
    const float* h_x = (const float*)d_in[0];
    const float* h_e = (const float*)d_in[1];
    const float* h_m = (const float*)d_in[2];
    const float* W_Q = (const float*)d_in[3];
    const float* W_K = (const float*)d_in[4];
    const float* W_V = (const float*)d_in[5];
    const float* W_R = (const float*)d_in[6];
    float* out = (float*)d_out;

    eama_fused<<<dim3(Bb * Nn), dim3(256), 0, stream>>>(
        h_x, h_e, h_m, W_Q, W_K, W_V, W_R, out);
}